// Round 3
// baseline (388.658 us; speedup 1.0000x reference)
//
#include <hip/hip_runtime.h>
#include <hip/hip_bf16.h>

typedef __attribute__((ext_vector_type(8))) __bf16 bf16x8;
typedef __attribute__((ext_vector_type(4))) __bf16 bf16x4;
typedef __attribute__((ext_vector_type(4))) float f32x4;

// qkv: (3,4,4096,256) fp32; conv_w: (256,1,3,3); conv_b: (256,) fp32
// windows: H_SP=64, W_SP=8 -> 8 col strips, WIN=512 tokens
// out = [ x: (4,4096,256) | attn: (32,8,512,512) ] fp32
// S^T formulation: QK MFMA computes D=K*Q^T so the C-layout gives
// q=lane&15 (col), c=quad*4+reg (row) -> lane-local softmax rows,
// b64 P writes, b128 P reads, coalesced attn stores.

__global__ __launch_bounds__(512, 2)
void lepe_attn(const float* __restrict__ qkv,
               const float* __restrict__ conv_w,
               const float* __restrict__ conv_b,
               float* __restrict__ out)
{
    constexpr int kL = 4096, kC = 256;
    constexpr int KSTR = 40;    // sK row stride (elems), 80 B: 16B-aligned rows
    constexpr int VSTR = 520;   // sVt row stride, 1040 B
    constexpr int PSTR = 264;   // sP row stride (256-c pass + pad), 528 B
    constexpr float SCALE = 0.17677669529663687f;  // 1/sqrt(32)

    __shared__ __align__(16) __bf16 sK [512 * KSTR];     // 40960 B  K[t][d]
    __shared__ __align__(16) __bf16 sVt[ 32 * VSTR];     // 33280 B  V^T[d][t]
    __shared__ __align__(16) __bf16 sP [8 * 16 * PSTR];  // 67584 B  per-wave P

    const int bx = blockIdx.x;        // 0..255 == wb*8 + h
    const int h  = bx & 7;
    const int wb = bx >> 3;
    const int b  = wb >> 3;
    const int w  = wb & 7;
    const int tid  = threadIdx.x;
    const int lane = tid & 63;
    const int wave = tid >> 6;        // 0..7
    const int l15  = lane & 15;
    const int quad = lane >> 4;

    const float* kBase = qkv + (size_t)4 * kL * kC;
    const float* vBase = qkv + (size_t)8 * kL * kC;

    // ---- stage K: thread owns 4 tokens x 8 d  (b128 LDS writes) ----
    {
        const int d0 = (tid & 3) * 8;
        const int t0 = (tid >> 2) * 4;
        #pragma unroll
        for (int i = 0; i < 4; ++i) {
            int t = t0 + i;
            int l = ((t >> 3) << 6) + (w << 3) + (t & 7);
            const float* p = kBase + ((size_t)(b * kL + l)) * kC + h * 32 + d0;
            f32x4 x0 = *(const f32x4*)p;
            f32x4 x1 = *(const f32x4*)(p + 4);
            bf16x8 kk;
            kk[0]=(__bf16)x0[0]; kk[1]=(__bf16)x0[1]; kk[2]=(__bf16)x0[2]; kk[3]=(__bf16)x0[3];
            kk[4]=(__bf16)x1[0]; kk[5]=(__bf16)x1[1]; kk[6]=(__bf16)x1[2]; kk[7]=(__bf16)x1[3];
            *(bf16x8*)&sK[t * KSTR + d0] = kk;
        }
    }
    // ---- stage V^T: thread owns 8 tokens x 4 d, register transpose, b128 writes ----
    {
        const int d0 = (tid & 7) * 4;
        const int t0 = (tid >> 3) * 8;                 // aligned to 8 -> one image row
        const int lrow = ((t0 >> 3) << 6) + (w << 3);  // t&7 = i
        const float* p = vBase + ((size_t)(b * kL + lrow)) * kC + h * 32 + d0;
        f32x4 vv[8];
        #pragma unroll
        for (int i = 0; i < 8; ++i) vv[i] = *(const f32x4*)(p + (size_t)i * kC);
        #pragma unroll
        for (int j = 0; j < 4; ++j) {
            bf16x8 row;
            #pragma unroll
            for (int i = 0; i < 8; ++i) row[i] = (__bf16)vv[i][j];
            *(bf16x8*)&sVt[(d0 + j) * VSTR + t0] = row;
        }
    }

    // ---- LePE conv weights for this thread's 2 channels ----
    float w9[2][9], wbias[2];
    #pragma unroll
    for (int nt = 0; nt < 2; ++nt) {
        int c = h * 32 + nt * 16 + l15;
        #pragma unroll
        for (int k = 0; k < 9; ++k) w9[nt][k] = conv_w[c * 9 + k];
        wbias[nt] = conv_b[c];
    }

    __syncthreads();

    float* attnOut = out + (size_t)4 * kL * kC;
    __bf16* sPw = &sP[wave * 16 * PSTR];

    for (int qt = 0; qt < 4; ++qt) {
        const int qrow0 = (wave * 4 + qt) * 16;   // this wave's 16 q rows

        // B fragment: Q[qrow0+l15][quad*8..+7], pre-scaled, fp32->bf16
        int tq = qrow0 + l15;
        int lq = ((tq >> 3) << 6) + (w << 3) + (tq & 7);
        const float* qp = qkv + ((size_t)(b * kL + lq)) * kC + h * 32 + quad * 8;
        f32x4 q0 = *(const f32x4*)qp;
        f32x4 q1 = *(const f32x4*)(qp + 4);
        bf16x8 qfrag;
        qfrag[0]=(__bf16)(q0[0]*SCALE); qfrag[1]=(__bf16)(q0[1]*SCALE);
        qfrag[2]=(__bf16)(q0[2]*SCALE); qfrag[3]=(__bf16)(q0[3]*SCALE);
        qfrag[4]=(__bf16)(q1[0]*SCALE); qfrag[5]=(__bf16)(q1[1]*SCALE);
        qfrag[6]=(__bf16)(q1[2]*SCALE); qfrag[7]=(__bf16)(q1[3]*SCALE);

        // ---- S^T = K Q^T : D[c][q], c=quad*4+r per tile, q=l15 ----
        f32x4 accS[32];
        const f32x4 zf = {0.f, 0.f, 0.f, 0.f};
        #pragma unroll
        for (int nt = 0; nt < 32; ++nt) {
            bf16x8 kfrag = *(const bf16x8*)&sK[(nt * 16 + l15) * KSTR + quad * 8];
            accS[nt] = __builtin_amdgcn_mfma_f32_16x16x32_bf16(kfrag, qfrag, zf, 0, 0, 0);
        }

        // ---- softmax along c: lane-local over 128 + cross-quad (xor 16,32) ----
        float m = -3.0e38f;
        #pragma unroll
        for (int nt = 0; nt < 32; ++nt)
            #pragma unroll
            for (int r = 0; r < 4; ++r) m = fmaxf(m, accS[nt][r]);
        m = fmaxf(m, __shfl_xor(m, 16));
        m = fmaxf(m, __shfl_xor(m, 32));
        float s = 0.f;
        #pragma unroll
        for (int nt = 0; nt < 32; ++nt)
            #pragma unroll
            for (int r = 0; r < 4; ++r) {
                float e = __expf(accS[nt][r] - m);
                accS[nt][r] = e;
                s += e;
            }
        s += __shfl_xor(s, 16);
        s += __shfl_xor(s, 32);
        const float inv = 1.0f / s;

        // ---- PV in 2 passes of 256 c; accumulate O across passes ----
        f32x4 accO0 = {0.f,0.f,0.f,0.f}, accO1 = {0.f,0.f,0.f,0.f};
        #pragma unroll
        for (int p = 0; p < 2; ++p) {
            // P -> LDS, packed b64 (lane holds 4 consecutive c of row q=l15)
            #pragma unroll
            for (int ntl = 0; ntl < 16; ++ntl) {
                const f32x4 a = accS[p * 16 + ntl];
                bf16x4 pk;
                pk[0]=(__bf16)(a[0]*inv); pk[1]=(__bf16)(a[1]*inv);
                pk[2]=(__bf16)(a[2]*inv); pk[3]=(__bf16)(a[3]*inv);
                *(bf16x4*)&sPw[l15 * PSTR + ntl * 16 + quad * 4] = pk;
            }
            // O += P V  (A = P rows b128, B = V^T rows b128)
            #pragma unroll
            for (int ktl = 0; ktl < 8; ++ktl) {
                bf16x8 pa  = *(const bf16x8*)&sPw[l15 * PSTR + ktl * 32 + quad * 8];
                const int c0 = p * 256 + ktl * 32 + quad * 8;
                bf16x8 vb0 = *(const bf16x8*)&sVt[ l15        * VSTR + c0];
                bf16x8 vb1 = *(const bf16x8*)&sVt[(16 + l15) * VSTR + c0];
                accO0 = __builtin_amdgcn_mfma_f32_16x16x32_bf16(pa, vb0, accO0, 0, 0, 0);
                accO1 = __builtin_amdgcn_mfma_f32_16x16x32_bf16(pa, vb1, accO1, 0, 0, 0);
            }
            // attn out: coalesced dwordx4 stores from the LDS copy
            const int row = lane >> 2;
            const int cof = (lane & 3) * 4;
            const size_t rbase = ((size_t)bx * 512 + qrow0 + row) * 512 + p * 256 + cof;
            #pragma unroll
            for (int u = 0; u < 16; ++u) {
                bf16x4 pv = *(const bf16x4*)&sPw[row * PSTR + u * 16 + cof];
                f32x4 o;
                o[0]=(float)pv[0]; o[1]=(float)pv[1]; o[2]=(float)pv[2]; o[3]=(float)pv[3];
                *(f32x4*)&attnOut[rbase + u * 16] = o;
            }
        }

        // ---- epilogue: + LePE 3x3 depthwise from sVt, write x ----
        const int t0  = qrow0 + quad * 4;     // 4 consecutive tokens, same image row
        const int r0  = t0 >> 3;
        const int cw0 = t0 & 7;               // 0 or 4
        #pragma unroll
        for (int nt = 0; nt < 2; ++nt) {
            const int dch = nt * 16 + l15;
            float patch[3][6];
            #pragma unroll
            for (int i = 0; i < 3; ++i) {
                int r2 = r0 - 1 + i;
                #pragma unroll
                for (int j = 0; j < 6; ++j) {
                    int c2 = cw0 - 1 + j;
                    bool ok = (r2 >= 0) && (r2 < 64) && (c2 >= 0) && (c2 < 8);
                    patch[i][j] = ok ? (float)sVt[dch * VSTR + r2 * 8 + c2] : 0.0f;
                }
            }
            #pragma unroll
            for (int r = 0; r < 4; ++r) {
                float acc = (nt ? accO1[r] : accO0[r]) + wbias[nt];
                #pragma unroll
                for (int i = 0; i < 3; ++i)
                    #pragma unroll
                    for (int jj = 0; jj < 3; ++jj)
                        acc += w9[nt][i * 3 + jj] * patch[i][r + jj];
                int trow = t0 + r;
                int lo = ((trow >> 3) << 6) + (w << 3) + (trow & 7);
                out[((size_t)(b * kL + lo)) * kC + h * 32 + dch] = acc;
            }
        }
    }
}

extern "C" void kernel_launch(void* const* d_in, const int* in_sizes, int n_in,
                              void* d_out, int out_size, void* d_ws, size_t ws_size,
                              hipStream_t stream) {
    const float* qkv = (const float*)d_in[0];
    const float* cw  = (const float*)d_in[1];
    const float* cb  = (const float*)d_in[2];
    float* outp = (float*)d_out;
    lepe_attn<<<dim3(256), dim3(512), 0, stream>>>(qkv, cw, cb, outp);
}